// Round 1
// baseline (665.901 us; speedup 1.0000x reference)
//
#include <hip/hip_runtime.h>
#include <cstdint>

typedef __attribute__((ext_vector_type(8))) short bf16x8;
typedef __attribute__((ext_vector_type(4))) float f32x4;
typedef unsigned short u16;

// round-to-nearest-even f32 -> bf16 bits
__device__ inline u16 f2bf(float f) {
  union { float f; unsigned int u; } v; v.f = f;
  unsigned int u = v.u;
  unsigned int r = (u + 0x7fffu + ((u >> 16) & 1u)) >> 16;
  return (u16)r;
}

__device__ inline void gload_lds16(const u16* g, u16* l) {
  __builtin_amdgcn_global_load_lds(
      (const __attribute__((address_space(1))) void*)g,
      (__attribute__((address_space(3))) void*)l, 16, 0, 0);
}

// ---- conversion: n8 groups of 8 floats -> 8 bf16 ----
__global__ void cvt_f32_bf16(const float* __restrict__ src, u16* __restrict__ dst, int n8) {
  int i = blockIdx.x * blockDim.x + threadIdx.x;
  int stride = gridDim.x * blockDim.x;
  for (; i < n8; i += stride) {
    const float4* s = (const float4*)(src + (size_t)i * 8);
    float4 a = s[0], b = s[1];
    union { u16 h[8]; uint4 v; } o;
    o.h[0] = f2bf(a.x); o.h[1] = f2bf(a.y); o.h[2] = f2bf(a.z); o.h[3] = f2bf(a.w);
    o.h[4] = f2bf(b.x); o.h[5] = f2bf(b.y); o.h[6] = f2bf(b.z); o.h[7] = f2bf(b.w);
    *(uint4*)(dst + (size_t)i * 8) = o.v;
  }
}

// ---- fused gate+up: per block n, C1 = X_n * W1_n^T, C3 = X_n * W3_n^T,
//      h = silu(C1) * C3 (bf16). X rows stride 2048, W rows stride 512 (K-contig).
__launch_bounds__(256, 2)
__global__ void gemm_gateup(const u16* __restrict__ xb, const u16* __restrict__ w1b,
                            const u16* __restrict__ w3b, u16* __restrict__ h) {
  int id = blockIdx.x;            // 128 row-tiles * 16 col-tiles * 4 blocks = 8192
  int nblk = id >> 11;
  int rem = id & 2047;
  int rt = rem >> 4;
  int ct = rem & 15;
  int row0 = rt * 128;
  int col0 = ct * 128;

  __shared__ __attribute__((aligned(16))) u16 sA[128 * 64];
  __shared__ __attribute__((aligned(16))) u16 sB1[128 * 64];
  __shared__ __attribute__((aligned(16))) u16 sB3[128 * 64];

  int t = threadIdx.x;
  int wave = t >> 6;
  int lane = t & 63;
  int wr = wave >> 1, wc = wave & 1;

  const u16* Abase  = xb  + (size_t)row0 * 2048 + nblk * 512;
  const u16* B1base = w1b + (size_t)nblk * (2048 * 512) + (size_t)col0 * 512;
  const u16* B3base = w3b + (size_t)nblk * (2048 * 512) + (size_t)col0 * 512;

  f32x4 acc1[4][4], acc3[4][4];
#pragma unroll
  for (int i = 0; i < 4; i++)
#pragma unroll
    for (int j = 0; j < 4; j++) {
      acc1[i][j] = (f32x4){0.f, 0.f, 0.f, 0.f};
      acc3[i][j] = (f32x4){0.f, 0.f, 0.f, 0.f};
    }

  for (int kt = 0; kt < 8; ++kt) {
    int k0 = kt * 64;
    if (kt) __syncthreads();
#pragma unroll
    for (int i = 0; i < 4; ++i) {
      int flat = i * 2048 + t * 8;   // element index in [128][64] tile
      int r = flat >> 6, c = flat & 63;
      gload_lds16(Abase  + (size_t)r * 2048 + k0 + c, &sA [i * 2048 + wave * 512]);
      gload_lds16(B1base + (size_t)r * 512  + k0 + c, &sB1[i * 2048 + wave * 512]);
      gload_lds16(B3base + (size_t)r * 512  + k0 + c, &sB3[i * 2048 + wave * 512]);
    }
    __syncthreads();
#pragma unroll
    for (int kk = 0; kk < 2; ++kk) {
      int ko = kk * 32 + (lane >> 4) * 8;
      bf16x8 a[4], b1[4], b3[4];
#pragma unroll
      for (int i = 0; i < 4; i++)
        a[i] = *(const bf16x8*)&sA[(wr * 64 + i * 16 + (lane & 15)) * 64 + ko];
#pragma unroll
      for (int j = 0; j < 4; j++) {
        b1[j] = *(const bf16x8*)&sB1[(wc * 64 + j * 16 + (lane & 15)) * 64 + ko];
        b3[j] = *(const bf16x8*)&sB3[(wc * 64 + j * 16 + (lane & 15)) * 64 + ko];
      }
#pragma unroll
      for (int i = 0; i < 4; i++)
#pragma unroll
        for (int j = 0; j < 4; j++) {
          acc1[i][j] = __builtin_amdgcn_mfma_f32_16x16x32_bf16(a[i], b1[j], acc1[i][j], 0, 0, 0);
          acc3[i][j] = __builtin_amdgcn_mfma_f32_16x16x32_bf16(a[i], b3[j], acc3[i][j], 0, 0, 0);
        }
    }
  }

  // epilogue: h[row][nblk*2048 + col] = silu(gate) * up
  u16* Hbase = h + (size_t)row0 * 8192 + nblk * 2048 + col0;
#pragma unroll
  for (int i = 0; i < 4; i++)
#pragma unroll
    for (int j = 0; j < 4; j++) {
      int coll = wc * 64 + j * 16 + (lane & 15);
      int rowb = wr * 64 + i * 16 + (lane >> 4) * 4;
#pragma unroll
      for (int r = 0; r < 4; r++) {
        float g = acc1[i][j][r];
        float u = acc3[i][j][r];
        float s = g / (1.f + __expf(-g));
        Hbase[(size_t)(rowb + r) * 8192 + coll] = f2bf(s * u);
      }
    }
}

// ---- down projection: per block n, out = H_n * W2_n^T (fp32 out) ----
__launch_bounds__(256, 3)
__global__ void gemm_down(const u16* __restrict__ h, const u16* __restrict__ w2b,
                          float* __restrict__ out) {
  int id = blockIdx.x;            // 128 row-tiles * 4 col-tiles * 4 blocks = 2048
  int nblk = id >> 9;
  int rem = id & 511;
  int rt = rem >> 2;
  int ct = rem & 3;
  int row0 = rt * 128, col0 = ct * 128;

  __shared__ __attribute__((aligned(16))) u16 sA[128 * 64];
  __shared__ __attribute__((aligned(16))) u16 sB[128 * 64];

  int t = threadIdx.x, wave = t >> 6, lane = t & 63;
  int wr = wave >> 1, wc = wave & 1;

  const u16* Abase = h   + (size_t)row0 * 8192 + nblk * 2048;
  const u16* Bbase = w2b + (size_t)nblk * (512 * 2048) + (size_t)col0 * 2048;

  f32x4 acc[4][4];
#pragma unroll
  for (int i = 0; i < 4; i++)
#pragma unroll
    for (int j = 0; j < 4; j++) acc[i][j] = (f32x4){0.f, 0.f, 0.f, 0.f};

  for (int kt = 0; kt < 32; ++kt) {
    int k0 = kt * 64;
    if (kt) __syncthreads();
#pragma unroll
    for (int i = 0; i < 4; ++i) {
      int flat = i * 2048 + t * 8;
      int r = flat >> 6, c = flat & 63;
      gload_lds16(Abase + (size_t)r * 8192 + k0 + c, &sA[i * 2048 + wave * 512]);
      gload_lds16(Bbase + (size_t)r * 2048 + k0 + c, &sB[i * 2048 + wave * 512]);
    }
    __syncthreads();
#pragma unroll
    for (int kk = 0; kk < 2; ++kk) {
      int ko = kk * 32 + (lane >> 4) * 8;
      bf16x8 a[4], b[4];
#pragma unroll
      for (int i = 0; i < 4; i++)
        a[i] = *(const bf16x8*)&sA[(wr * 64 + i * 16 + (lane & 15)) * 64 + ko];
#pragma unroll
      for (int j = 0; j < 4; j++)
        b[j] = *(const bf16x8*)&sB[(wc * 64 + j * 16 + (lane & 15)) * 64 + ko];
#pragma unroll
      for (int i = 0; i < 4; i++)
#pragma unroll
        for (int j = 0; j < 4; j++)
          acc[i][j] = __builtin_amdgcn_mfma_f32_16x16x32_bf16(a[i], b[j], acc[i][j], 0, 0, 0);
    }
  }

  float* Obase = out + (size_t)row0 * 2048 + nblk * 512 + col0;
#pragma unroll
  for (int i = 0; i < 4; i++)
#pragma unroll
    for (int j = 0; j < 4; j++) {
      int coll = wc * 64 + j * 16 + (lane & 15);
      int rowb = wr * 64 + i * 16 + (lane >> 4) * 4;
#pragma unroll
      for (int r = 0; r < 4; r++)
        Obase[(size_t)(rowb + r) * 2048 + coll] = acc[i][j][r];
    }
}

extern "C" void kernel_launch(void* const* d_in, const int* in_sizes, int n_in,
                              void* d_out, int out_size, void* d_ws, size_t ws_size,
                              hipStream_t stream) {
  const float* x  = (const float*)d_in[0];
  const float* w1 = (const float*)d_in[1];
  const float* w3 = (const float*)d_in[2];
  const float* w2 = (const float*)d_in[3];

  char* ws = (char*)d_ws;
  u16* xb  = (u16*)(ws);                 // 33,554,432 elems = 64 MiB
  u16* w1b = (u16*)(ws + 67108864);      // 4,194,304 elems = 8 MiB
  u16* w3b = (u16*)(ws + 75497472);
  u16* w2b = (u16*)(ws + 83886080);
  u16* h   = (u16*)(ws + 92274688);      // 134,217,728 elems = 256 MiB

  cvt_f32_bf16<<<2048, 256, 0, stream>>>(x,  xb,  33554432 / 8);
  cvt_f32_bf16<<<2048, 256, 0, stream>>>(w1, w1b, 4194304 / 8);
  cvt_f32_bf16<<<2048, 256, 0, stream>>>(w3, w3b, 4194304 / 8);
  cvt_f32_bf16<<<2048, 256, 0, stream>>>(w2, w2b, 4194304 / 8);

  gemm_gateup<<<8192, 256, 0, stream>>>(xb, w1b, w3b, h);
  gemm_down<<<2048, 256, 0, stream>>>(h, w2b, (float*)d_out);
}

// Round 2
// 627.434 us; speedup vs baseline: 1.0613x; 1.0613x over previous
//
#include <hip/hip_runtime.h>
#include <cstdint>

typedef __attribute__((ext_vector_type(8))) short bf16x8;
typedef __attribute__((ext_vector_type(4))) float f32x4;
typedef unsigned short u16;

__device__ inline u16 f2bf(float f) {
  union { float f; unsigned int u; } v; v.f = f;
  unsigned int u = v.u;
  unsigned int r = (u + 0x7fffu + ((u >> 16) & 1u)) >> 16;
  return (u16)r;
}

__device__ inline void gload_lds16(const u16* g, u16* l) {
  __builtin_amdgcn_global_load_lds(
      (const __attribute__((address_space(1))) void*)g,
      (__attribute__((address_space(3))) void*)l, 16, 0, 0);
}

// Stage one 16 KiB half-tile (128 rows x 128B) with XOR-swizzled global source.
// Row pattern: rows = rOff + (i/BS)*ST + (i%BS), i = flat half-row index.
// LDS dest is linear [row][64 elems]; content is column-swizzled via source.
template<int BS, int ST>
__device__ inline void stg(const u16* g, int gs, u16* ldsT, int rOff,
                           int w, int lr, int swz) {
#pragma unroll
  for (int l = 0; l < 2; ++l) {
    int i0 = l * 64 + w * 8;
    int rb = rOff + (i0 / BS) * ST + (i0 % BS);
    gload_lds16(g + (size_t)(rb + lr) * gs + swz, ldsT + rb * 64);
  }
}

// swizzled fragment read: logical (row r, col-group cc in units of 8 elems)
__device__ inline bf16x8 frd(const u16* ldsT, int r, int cc) {
  return *(const bf16x8*)&ldsT[r * 64 + ((cc ^ (r & 7)) << 3)];
}

#define PH_SYNC_BEGIN() \
  __builtin_amdgcn_s_barrier(); \
  asm volatile("s_waitcnt lgkmcnt(0)" ::: "memory"); \
  __builtin_amdgcn_s_setprio(1)
#define PH_SYNC_END() \
  __builtin_amdgcn_s_setprio(0); \
  __builtin_amdgcn_s_barrier()

// ---- conversion: n8 groups of 8 floats -> 8 bf16 ----
__global__ void cvt_f32_bf16(const float* __restrict__ src, u16* __restrict__ dst, int n8) {
  int i = blockIdx.x * blockDim.x + threadIdx.x;
  int stride = gridDim.x * blockDim.x;
  for (; i < n8; i += stride) {
    const float4* s = (const float4*)(src + (size_t)i * 8);
    float4 a = s[0], b = s[1];
    union { u16 h[8]; uint4 v; } o;
    o.h[0] = f2bf(a.x); o.h[1] = f2bf(a.y); o.h[2] = f2bf(a.z); o.h[3] = f2bf(a.w);
    o.h[4] = f2bf(b.x); o.h[5] = f2bf(b.y); o.h[6] = f2bf(b.z); o.h[7] = f2bf(b.w);
    *(uint4*)(dst + (size_t)i * 8) = o.v;
  }
}

// ==================== fused gate+up, 8-phase 256x128 tile ====================
// Per nblk: C1 = X_n(16384x512) * W1_n^T, C3 = X_n * W3_n^T, h = silu(C1)*C3.
__launch_bounds__(512, 2)
__global__ void gemm_gateup8(const u16* __restrict__ xb, const u16* __restrict__ w1b,
                             const u16* __restrict__ w3b, u16* __restrict__ hout) {
  constexpr int NT = 8;  // K = 512 / 64
  __shared__ __attribute__((aligned(16))) u16 lA_[2][256 * 64];
  __shared__ __attribute__((aligned(16))) u16 lB1_[2][128 * 64];
  __shared__ __attribute__((aligned(16))) u16 lB3_[2][128 * 64];

  int bid = blockIdx.x;
  int sw = (bid & 7) * 512 + (bid >> 3);   // 4096 wg, bijective (4096 % 8 == 0)
  int nblk = sw >> 10;
  int rem = sw & 1023;
  int mt = rem >> 4, nt = rem & 15;

  int tid = threadIdx.x, w = tid >> 6, ln = tid & 63;
  int lr = ln >> 3;
  int swz = ((ln & 7) ^ lr) << 3;
  int wr = w >> 1, wc = w & 1;
  int l15 = ln & 15, l4 = ln >> 4;

  const u16* Ag  = xb  + (size_t)(mt * 256) * 2048 + nblk * 512;
  const u16* B1g = w1b + (size_t)nblk * (2048 * 512) + (size_t)(nt * 128) * 512;
  const u16* B3g = w3b + (size_t)nblk * (2048 * 512) + (size_t)(nt * 128) * 512;

  f32x4 acc1[4][4], acc3[4][4];
#pragma unroll
  for (int i = 0; i < 4; i++)
#pragma unroll
    for (int j = 0; j < 4; j++) {
      acc1[i][j] = (f32x4){0.f, 0.f, 0.f, 0.f};
      acc3[i][j] = (f32x4){0.f, 0.f, 0.f, 0.f};
    }

  // prologue: t0.{A-lo, B3, A-hi, B1}, t1.{A-lo, B3, A-hi}
  stg<32, 64>(Ag, 2048, lA_[0], 0, w, lr, swz);
  stg<128, 128>(B3g, 512, lB3_[0], 0, w, lr, swz);
  stg<32, 64>(Ag, 2048, lA_[0], 32, w, lr, swz);
  stg<128, 128>(B1g, 512, lB1_[0], 0, w, lr, swz);
  stg<32, 64>(Ag + 64, 2048, lA_[1], 0, w, lr, swz);
  stg<128, 128>(B3g + 64, 512, lB3_[1], 0, w, lr, swz);
  stg<32, 64>(Ag + 64, 2048, lA_[1], 32, w, lr, swz);
  asm volatile("s_waitcnt vmcnt(6)" ::: "memory");
  __builtin_amdgcn_s_barrier();

  bf16x8 aL[2][2], aH[2][2], b1[4][2], b3[4][2];

  for (int kt = 0; kt < NT; ++kt) {
    u16* cA = lA_[kt & 1]; u16* cB1 = lB1_[kt & 1]; u16* cB3 = lB3_[kt & 1];
    u16* nB1 = lB1_[(kt + 1) & 1];
    const u16* gA2 = Ag + (kt + 2) * 64;
    const u16* gB32 = B3g + (kt + 2) * 64;
    const u16* gB1n = B1g + (kt + 1) * 64;
    bool s1 = (kt + 1 < NT), s2 = (kt + 2 < NT);

    // ---- P0: read A-lo frags + all B1 frags; stage next.B1 (other buffer)
#pragma unroll
    for (int f = 0; f < 2; ++f)
#pragma unroll
      for (int ks = 0; ks < 2; ++ks)
        aL[f][ks] = frd(cA, wr * 64 + f * 16 + l15, ks * 4 + l4);
#pragma unroll
    for (int g = 0; g < 4; ++g)
#pragma unroll
      for (int ks = 0; ks < 2; ++ks)
        b1[g][ks] = frd(cB1, wc * 64 + g * 16 + l15, ks * 4 + l4);
    if (s1) stg<128, 128>(gB1n, 512, nB1, 0, w, lr, swz);
    PH_SYNC_BEGIN();
#pragma unroll
    for (int f = 0; f < 2; ++f)
#pragma unroll
      for (int g = 0; g < 4; ++g)
#pragma unroll
        for (int ks = 0; ks < 2; ++ks)
          acc1[f][g] = __builtin_amdgcn_mfma_f32_16x16x32_bf16(aL[f][ks], b1[g][ks], acc1[f][g], 0, 0, 0);
    PH_SYNC_END();

    // ---- P1: read all B3 frags; stage t+2.A-lo (consumed in P0)
#pragma unroll
    for (int g = 0; g < 4; ++g)
#pragma unroll
      for (int ks = 0; ks < 2; ++ks)
        b3[g][ks] = frd(cB3, wc * 64 + g * 16 + l15, ks * 4 + l4);
    if (s2) stg<32, 64>(gA2, 2048, cA, 0, w, lr, swz);
    PH_SYNC_BEGIN();
#pragma unroll
    for (int f = 0; f < 2; ++f)
#pragma unroll
      for (int g = 0; g < 4; ++g)
#pragma unroll
        for (int ks = 0; ks < 2; ++ks)
          acc3[f][g] = __builtin_amdgcn_mfma_f32_16x16x32_bf16(aL[f][ks], b3[g][ks], acc3[f][g], 0, 0, 0);
    PH_SYNC_END();

    // ---- P2: read A-hi frags; stage t+2.B3 (consumed in P1)
#pragma unroll
    for (int f = 0; f < 2; ++f)
#pragma unroll
      for (int ks = 0; ks < 2; ++ks)
        aH[f][ks] = frd(cA, wr * 64 + 32 + f * 16 + l15, ks * 4 + l4);
    if (s2) stg<128, 128>(gB32, 512, cB3, 0, w, lr, swz);
    PH_SYNC_BEGIN();
#pragma unroll
    for (int f = 0; f < 2; ++f)
#pragma unroll
      for (int g = 0; g < 4; ++g)
#pragma unroll
        for (int ks = 0; ks < 2; ++ks)
          acc1[2 + f][g] = __builtin_amdgcn_mfma_f32_16x16x32_bf16(aH[f][ks], b1[g][ks], acc1[2 + f][g], 0, 0, 0);
    PH_SYNC_END();

    // ---- P3: no reads; stage t+2.A-hi (consumed in P2); trailing vmcnt
    if (s2) stg<32, 64>(gA2, 2048, cA, 32, w, lr, swz);
    PH_SYNC_BEGIN();
#pragma unroll
    for (int f = 0; f < 2; ++f)
#pragma unroll
      for (int g = 0; g < 4; ++g)
#pragma unroll
        for (int ks = 0; ks < 2; ++ks)
          acc3[2 + f][g] = __builtin_amdgcn_mfma_f32_16x16x32_bf16(aH[f][ks], b3[g][ks], acc3[2 + f][g], 0, 0, 0);
    __builtin_amdgcn_s_setprio(0);
    if (kt < NT - 2)      asm volatile("s_waitcnt vmcnt(6)" ::: "memory");
    else if (kt == NT - 2) asm volatile("s_waitcnt vmcnt(0)" ::: "memory");
    __builtin_amdgcn_s_barrier();
  }

  // epilogue: h = silu(gate) * up, bf16
  u16* Hb = hout + (size_t)(mt * 256 + wr * 64) * 8192 + nblk * 2048 + nt * 128 + wc * 64;
#pragma unroll
  for (int f = 0; f < 4; ++f)
#pragma unroll
    for (int g = 0; g < 4; ++g) {
      int col = g * 16 + l15;
#pragma unroll
      for (int r = 0; r < 4; ++r) {
        int row = f * 16 + l4 * 4 + r;
        float gate = acc1[f][g][r];
        float up = acc3[f][g][r];
        float s = gate / (1.f + __expf(-gate));
        Hb[(size_t)row * 8192 + col] = f2bf(s * up);
      }
    }
}

// ==================== down projection, 8-phase 256x256 tile ====================
__launch_bounds__(512, 2)
__global__ void gemm_down8(const u16* __restrict__ hmat, const u16* __restrict__ w2b,
                           float* __restrict__ out) {
  constexpr int NT = 32;  // K = 2048 / 64
  __shared__ __attribute__((aligned(16))) u16 lA_[2][256 * 64];
  __shared__ __attribute__((aligned(16))) u16 lB_[2][256 * 64];

  int bid = blockIdx.x;
  int sw = (bid & 7) * 64 + (bid >> 3);   // 512 wg
  int nblk = sw >> 7;
  int rem = sw & 127;
  int mt = rem >> 1, nt = rem & 1;

  int tid = threadIdx.x, w = tid >> 6, ln = tid & 63;
  int lr = ln >> 3;
  int swz = ((ln & 7) ^ lr) << 3;
  int mi = w >> 2, nj = w & 3;
  int l15 = ln & 15, l4 = ln >> 4;

  const u16* Ag = hmat + (size_t)(mt * 256) * 8192 + nblk * 2048;
  const u16* Bg = w2b + (size_t)nblk * (512 * 2048) + (size_t)(nt * 256) * 2048;

  f32x4 acc[8][4];
#pragma unroll
  for (int i = 0; i < 8; i++)
#pragma unroll
    for (int j = 0; j < 4; j++) acc[i][j] = (f32x4){0.f, 0.f, 0.f, 0.f};

  // prologue: t0.{A-lo, B-hi, A-hi, B-lo}, t1.{A-lo, B-hi, A-hi}
  stg<64, 128>(Ag, 8192, lA_[0], 0, w, lr, swz);
  stg<32, 64>(Bg, 2048, lB_[0], 32, w, lr, swz);
  stg<64, 128>(Ag, 8192, lA_[0], 64, w, lr, swz);
  stg<32, 64>(Bg, 2048, lB_[0], 0, w, lr, swz);
  stg<64, 128>(Ag + 64, 8192, lA_[1], 0, w, lr, swz);
  stg<32, 64>(Bg + 64, 2048, lB_[1], 32, w, lr, swz);
  stg<64, 128>(Ag + 64, 8192, lA_[1], 64, w, lr, swz);
  asm volatile("s_waitcnt vmcnt(6)" ::: "memory");
  __builtin_amdgcn_s_barrier();

  bf16x8 aF[4][2], bLo[2][2], bHi[2][2];

  for (int kt = 0; kt < NT; ++kt) {
    u16* cA = lA_[kt & 1]; u16* cB = lB_[kt & 1];
    u16* nB = lB_[(kt + 1) & 1];
    const u16* gA2 = Ag + (kt + 2) * 64;
    const u16* gB2 = Bg + (kt + 2) * 64;
    const u16* gBn = Bg + (kt + 1) * 64;
    bool s1 = (kt + 1 < NT), s2 = (kt + 2 < NT);

    // ---- P0: read A f0-3 + B-lo; stage next.B-lo (other buffer)
#pragma unroll
    for (int f = 0; f < 4; ++f)
#pragma unroll
      for (int ks = 0; ks < 2; ++ks)
        aF[f][ks] = frd(cA, mi * 128 + f * 16 + l15, ks * 4 + l4);
#pragma unroll
    for (int g = 0; g < 2; ++g)
#pragma unroll
      for (int ks = 0; ks < 2; ++ks)
        bLo[g][ks] = frd(cB, nj * 64 + g * 16 + l15, ks * 4 + l4);
    if (s1) stg<32, 64>(gBn, 2048, nB, 0, w, lr, swz);
    PH_SYNC_BEGIN();
#pragma unroll
    for (int f = 0; f < 4; ++f)
#pragma unroll
      for (int g = 0; g < 2; ++g)
#pragma unroll
        for (int ks = 0; ks < 2; ++ks)
          acc[f][g] = __builtin_amdgcn_mfma_f32_16x16x32_bf16(aF[f][ks], bLo[g][ks], acc[f][g], 0, 0, 0);
    PH_SYNC_END();

    // ---- P1: read B-hi; stage t+2.A-lo (consumed in P0)
#pragma unroll
    for (int g = 0; g < 2; ++g)
#pragma unroll
      for (int ks = 0; ks < 2; ++ks)
        bHi[g][ks] = frd(cB, nj * 64 + 32 + g * 16 + l15, ks * 4 + l4);
    if (s2) stg<64, 128>(gA2, 8192, cA, 0, w, lr, swz);
    PH_SYNC_BEGIN();
#pragma unroll
    for (int f = 0; f < 4; ++f)
#pragma unroll
      for (int g = 0; g < 2; ++g)
#pragma unroll
        for (int ks = 0; ks < 2; ++ks)
          acc[f][2 + g] = __builtin_amdgcn_mfma_f32_16x16x32_bf16(aF[f][ks], bHi[g][ks], acc[f][2 + g], 0, 0, 0);
    PH_SYNC_END();

    // ---- P2: read A f4-7; stage t+2.B-hi (consumed in P1)
#pragma unroll
    for (int f = 0; f < 4; ++f)
#pragma unroll
      for (int ks = 0; ks < 2; ++ks)
        aF[f][ks] = frd(cA, mi * 128 + 64 + f * 16 + l15, ks * 4 + l4);
    if (s2) stg<32, 64>(gB2, 2048, cB, 32, w, lr, swz);
    PH_SYNC_BEGIN();
#pragma unroll
    for (int f = 0; f < 4; ++f)
#pragma unroll
      for (int g = 0; g < 2; ++g)
#pragma unroll
        for (int ks = 0; ks < 2; ++ks)
          acc[4 + f][g] = __builtin_amdgcn_mfma_f32_16x16x32_bf16(aF[f][ks], bLo[g][ks], acc[4 + f][g], 0, 0, 0);
    PH_SYNC_END();

    // ---- P3: no reads; stage t+2.A-hi (consumed in P2); trailing vmcnt
    if (s2) stg<64, 128>(gA2, 8192, cA, 64, w, lr, swz);
    PH_SYNC_BEGIN();
#pragma unroll
    for (int f = 0; f < 4; ++f)
#pragma unroll
      for (int g = 0; g < 2; ++g)
#pragma unroll
        for (int ks = 0; ks < 2; ++ks)
          acc[4 + f][2 + g] = __builtin_amdgcn_mfma_f32_16x16x32_bf16(aF[f][ks], bHi[g][ks], acc[4 + f][2 + g], 0, 0, 0);
    __builtin_amdgcn_s_setprio(0);
    if (kt < NT - 2)      asm volatile("s_waitcnt vmcnt(6)" ::: "memory");
    else if (kt == NT - 2) asm volatile("s_waitcnt vmcnt(0)" ::: "memory");
    __builtin_amdgcn_s_barrier();
  }

  float* Ob = out + (size_t)(mt * 256 + mi * 128) * 2048 + nblk * 512 + nt * 256 + nj * 64;
#pragma unroll
  for (int f = 0; f < 8; ++f)
#pragma unroll
    for (int g = 0; g < 4; ++g) {
      int col = g * 16 + l15;
#pragma unroll
      for (int r = 0; r < 4; ++r) {
        int row = f * 16 + l4 * 4 + r;
        Ob[(size_t)row * 2048 + col] = acc[f][g][r];
      }
    }
}

extern "C" void kernel_launch(void* const* d_in, const int* in_sizes, int n_in,
                              void* d_out, int out_size, void* d_ws, size_t ws_size,
                              hipStream_t stream) {
  const float* x  = (const float*)d_in[0];
  const float* w1 = (const float*)d_in[1];
  const float* w3 = (const float*)d_in[2];
  const float* w2 = (const float*)d_in[3];

  char* ws = (char*)d_ws;
  u16* xb  = (u16*)(ws);                 // 64 MiB
  u16* w1b = (u16*)(ws + 67108864);      // 8 MiB
  u16* w3b = (u16*)(ws + 75497472);
  u16* w2b = (u16*)(ws + 83886080);
  u16* h   = (u16*)(ws + 92274688);      // 256 MiB

  cvt_f32_bf16<<<2048, 256, 0, stream>>>(x,  xb,  33554432 / 8);
  cvt_f32_bf16<<<2048, 256, 0, stream>>>(w1, w1b, 4194304 / 8);
  cvt_f32_bf16<<<2048, 256, 0, stream>>>(w3, w3b, 4194304 / 8);
  cvt_f32_bf16<<<2048, 256, 0, stream>>>(w2, w2b, 4194304 / 8);

  gemm_gateup8<<<4096, 512, 0, stream>>>(xb, w1b, w3b, h);
  gemm_down8<<<512, 512, 0, stream>>>(h, w2b, (float*)d_out);
}

// Round 3
// 556.699 us; speedup vs baseline: 1.1962x; 1.1271x over previous
//
#include <hip/hip_runtime.h>
#include <cstdint>

typedef __attribute__((ext_vector_type(8))) short bf16x8;
typedef __attribute__((ext_vector_type(4))) float f32x4;
typedef unsigned short u16;

#define RD(p) (*(const bf16x8*)(p))

__device__ inline u16 f2bf(float f) {
  union { float f; unsigned int u; } v; v.f = f;
  unsigned int u = v.u;
  unsigned int r = (u + 0x7fffu + ((u >> 16) & 1u)) >> 16;
  return (u16)r;
}

__device__ inline void gload_lds16(const u16* g, u16* l) {
  __builtin_amdgcn_global_load_lds(
      (const __attribute__((address_space(1))) void*)g,
      (__attribute__((address_space(3))) void*)l, 16, 0, 0);
}

#define PH_BEGIN() \
  __builtin_amdgcn_s_barrier(); \
  asm volatile("s_waitcnt lgkmcnt(0)" ::: "memory"); \
  __builtin_amdgcn_s_setprio(1)
#define PH_END() \
  __builtin_amdgcn_s_setprio(0); \
  __builtin_amdgcn_s_barrier()

__global__ void cvt_f32_bf16(const float* __restrict__ src, u16* __restrict__ dst, int n8) {
  int i = blockIdx.x * blockDim.x + threadIdx.x;
  int stride = gridDim.x * blockDim.x;
  for (; i < n8; i += stride) {
    const float4* s = (const float4*)(src + (size_t)i * 8);
    float4 a = s[0], b = s[1];
    union { u16 h[8]; uint4 v; } o;
    o.h[0] = f2bf(a.x); o.h[1] = f2bf(a.y); o.h[2] = f2bf(a.z); o.h[3] = f2bf(a.w);
    o.h[4] = f2bf(b.x); o.h[5] = f2bf(b.y); o.h[6] = f2bf(b.z); o.h[7] = f2bf(b.w);
    *(uint4*)(dst + (size_t)i * 8) = o.v;
  }
}

// ==================== fused gate+up, 8-phase 256x128 tile, hoisted addresses ====================
__launch_bounds__(512, 2)
__global__ void gemm_gateup8(const u16* __restrict__ xb, const u16* __restrict__ w1b,
                             const u16* __restrict__ w3b, u16* __restrict__ hout) {
  constexpr int NT = 8;  // K = 512 / 64
  __shared__ __attribute__((aligned(16))) u16 lA[2][256 * 64];      // [buf], 32768 B each
  __shared__ __attribute__((aligned(16))) u16 lB[2][2][128 * 64];   // [buf][mat], mat stride 16384 B

  int bid = blockIdx.x;
  int sw = (bid & 7) * 512 + (bid >> 3);   // bijective, 4096 % 8 == 0
  int nblk = sw >> 10;
  int rem = sw & 1023;
  int mt = rem >> 4, nt = rem & 15;

  int tid = threadIdx.x, w = tid >> 6, ln = tid & 63;
  int wr = w >> 1, wc = w & 1;
  int l15 = ln & 15, l4 = ln >> 4;
  int lr = ln >> 3, ln8 = ln & 7;

  // ---- read offsets (bytes, rel buf0 of each array); 3-bit XOR swizzle ----
  int cx0 = ((l4 ^ (l15 & 7)) << 4);
  int cx1 = (((4 + l4) ^ (l15 & 7)) << 4);
  int aOff0 = (wr * 64 + l15) * 128 + cx0;
  int aOff1 = (wr * 64 + l15) * 128 + cx1;
  int bOff0 = (wc * 64 + l15) * 128 + cx0;
  int bOff1 = (wc * 64 + l15) * 128 + cx1;

  // ---- stage constants ----
  int u0t = w * 8, u1t = 64 + w * 8;
  int rbA0 = ((u0t >> 5) << 6) + (u0t & 31);
  int rbA1 = ((u1t >> 5) << 6) + (u1t & 31);
  int dA0 = rbA0 * 128, dA1 = rbA1 * 128;   // LDS dest bytes
  int dB0 = u0t * 128, dB1 = u1t * 128;
  int gaA0 = rbA0 * 2048, gaA1 = rbA1 * 2048;  // global row offs (elems)
  int gaB0 = u0t * 512, gaB1 = u1t * 512;
  int swzg = (ln8 ^ lr) << 3;

  const u16* gA  = xb  + (size_t)(mt * 256) * 2048 + nblk * 512 + lr * 2048 + swzg;
  const u16* gB1 = w1b + (size_t)nblk * (2048 * 512) + (size_t)(nt * 128) * 512 + lr * 512 + swzg;
  const u16* gB3 = w3b + (size_t)nblk * (2048 * 512) + (size_t)(nt * 128) * 512 + lr * 512 + swzg;

  f32x4 acc1[4][4], acc3[4][4];
#pragma unroll
  for (int i = 0; i < 4; i++)
#pragma unroll
    for (int j = 0; j < 4; j++) {
      acc1[i][j] = (f32x4){0.f, 0.f, 0.f, 0.f};
      acc3[i][j] = (f32x4){0.f, 0.f, 0.f, 0.f};
    }

  // prologue: t0.{Alo,B3,Ahi,B1}, t1.{Alo,B3,Ahi}
  gload_lds16(gA + gaA0,          (u16*)((char*)lA + dA0));
  gload_lds16(gA + gaA1,          (u16*)((char*)lA + dA1));
  gload_lds16(gB3 + gaB0,         (u16*)((char*)lB + 16384 + dB0));
  gload_lds16(gB3 + gaB1,         (u16*)((char*)lB + 16384 + dB1));
  gload_lds16(gA + gaA0 + 65536,  (u16*)((char*)lA + dA0 + 4096));
  gload_lds16(gA + gaA1 + 65536,  (u16*)((char*)lA + dA1 + 4096));
  gload_lds16(gB1 + gaB0,         (u16*)((char*)lB + dB0));
  gload_lds16(gB1 + gaB1,         (u16*)((char*)lB + dB1));
  gload_lds16(gA + 64 + gaA0,         (u16*)((char*)lA + 32768 + dA0));
  gload_lds16(gA + 64 + gaA1,         (u16*)((char*)lA + 32768 + dA1));
  gload_lds16(gB3 + 64 + gaB0,        (u16*)((char*)lB + 32768 + 16384 + dB0));
  gload_lds16(gB3 + 64 + gaB1,        (u16*)((char*)lB + 32768 + 16384 + dB1));
  gload_lds16(gA + 64 + gaA0 + 65536, (u16*)((char*)lA + 32768 + dA0 + 4096));
  gload_lds16(gA + 64 + gaA1 + 65536, (u16*)((char*)lA + 32768 + dA1 + 4096));
  gA += 128; gB3 += 128; gB1 += 64;
  asm volatile("s_waitcnt vmcnt(6)" ::: "memory");
  __builtin_amdgcn_s_barrier();

  int sCur = 0, sNxt = 32768;
  bf16x8 aT[2][2], aH[2][2], b1[4][2], b3[4][2];

  for (int kt = 0; kt < NT; ++kt) {
    const char* pA0 = (const char*)lA + (sCur + aOff0);
    const char* pA1 = (const char*)lA + (sCur + aOff1);
    const char* pB0 = (const char*)lB + (sCur + bOff0);
    const char* pB1p = (const char*)lB + (sCur + bOff1);
    bool s1 = (kt + 1 < NT), s2 = (kt + 2 < NT);

    // ---- P0: read A-lo + B1; stage t+1.B1 (other buf)
#pragma unroll
    for (int f = 0; f < 2; ++f) {
      aT[f][0] = RD(pA0 + f * 2048); aT[f][1] = RD(pA1 + f * 2048);
    }
#pragma unroll
    for (int g = 0; g < 4; ++g) {
      b1[g][0] = RD(pB0 + g * 2048); b1[g][1] = RD(pB1p + g * 2048);
    }
    if (s1) {
      gload_lds16(gB1 + gaB0, (u16*)((char*)lB + sNxt + dB0));
      gload_lds16(gB1 + gaB1, (u16*)((char*)lB + sNxt + dB1));
    }
    asm volatile("s_waitcnt lgkmcnt(8)" ::: "memory");
    PH_BEGIN();
#pragma unroll
    for (int f = 0; f < 2; ++f)
#pragma unroll
      for (int g = 0; g < 4; ++g)
#pragma unroll
        for (int ks = 0; ks < 2; ++ks)
          acc1[f][g] = __builtin_amdgcn_mfma_f32_16x16x32_bf16(aT[f][ks], b1[g][ks], acc1[f][g], 0, 0, 0);
    PH_END();

    // ---- P1: read B3; stage t+2.A-lo (cur buf)
#pragma unroll
    for (int g = 0; g < 4; ++g) {
      b3[g][0] = RD(pB0 + 16384 + g * 2048); b3[g][1] = RD(pB1p + 16384 + g * 2048);
    }
    if (s2) {
      gload_lds16(gA + gaA0, (u16*)((char*)lA + sCur + dA0));
      gload_lds16(gA + gaA1, (u16*)((char*)lA + sCur + dA1));
    }
    PH_BEGIN();
#pragma unroll
    for (int f = 0; f < 2; ++f)
#pragma unroll
      for (int g = 0; g < 4; ++g)
#pragma unroll
        for (int ks = 0; ks < 2; ++ks)
          acc3[f][g] = __builtin_amdgcn_mfma_f32_16x16x32_bf16(aT[f][ks], b3[g][ks], acc3[f][g], 0, 0, 0);
    PH_END();

    // ---- P2: read A-hi; stage t+2.B3 (cur buf)
#pragma unroll
    for (int f = 0; f < 2; ++f) {
      aH[f][0] = RD(pA0 + 4096 + f * 2048); aH[f][1] = RD(pA1 + 4096 + f * 2048);
    }
    if (s2) {
      gload_lds16(gB3 + gaB0, (u16*)((char*)lB + sCur + 16384 + dB0));
      gload_lds16(gB3 + gaB1, (u16*)((char*)lB + sCur + 16384 + dB1));
    }
    PH_BEGIN();
#pragma unroll
    for (int f = 0; f < 2; ++f)
#pragma unroll
      for (int g = 0; g < 4; ++g)
#pragma unroll
        for (int ks = 0; ks < 2; ++ks)
          acc1[2 + f][g] = __builtin_amdgcn_mfma_f32_16x16x32_bf16(aH[f][ks], b1[g][ks], acc1[2 + f][g], 0, 0, 0);
    PH_END();

    // ---- P3: stage t+2.A-hi (cur buf); trailing counted vmcnt
    if (s2) {
      gload_lds16(gA + gaA0 + 65536, (u16*)((char*)lA + sCur + dA0 + 4096));
      gload_lds16(gA + gaA1 + 65536, (u16*)((char*)lA + sCur + dA1 + 4096));
    }
    PH_BEGIN();
#pragma unroll
    for (int f = 0; f < 2; ++f)
#pragma unroll
      for (int g = 0; g < 4; ++g)
#pragma unroll
        for (int ks = 0; ks < 2; ++ks)
          acc3[2 + f][g] = __builtin_amdgcn_mfma_f32_16x16x32_bf16(aH[f][ks], b3[g][ks], acc3[2 + f][g], 0, 0, 0);
    __builtin_amdgcn_s_setprio(0);
    if (kt < NT - 2)       asm volatile("s_waitcnt vmcnt(6)" ::: "memory");
    else if (kt == NT - 2) asm volatile("s_waitcnt vmcnt(0)" ::: "memory");
    __builtin_amdgcn_s_barrier();
    gA += 64; gB1 += 64; gB3 += 64;
    sCur ^= 32768; sNxt ^= 32768;
  }

  // epilogue: h = silu(gate) * up, bf16
  u16* Hb = hout + (size_t)(mt * 256 + wr * 64) * 8192 + nblk * 2048 + nt * 128 + wc * 64;
#pragma unroll
  for (int f = 0; f < 4; ++f)
#pragma unroll
    for (int g = 0; g < 4; ++g) {
      int col = g * 16 + l15;
#pragma unroll
      for (int r = 0; r < 4; ++r) {
        int row = f * 16 + l4 * 4 + r;
        float gate = acc1[f][g][r];
        float up = acc3[f][g][r];
        float s = gate * __builtin_amdgcn_rcpf(1.f + __expf(-gate));
        Hb[(size_t)row * 8192 + col] = f2bf(s * up);
      }
    }
}

// ==================== down projection, 8-phase 256x256 tile, hoisted addresses ====================
__launch_bounds__(512, 2)
__global__ void gemm_down8(const u16* __restrict__ hmat, const u16* __restrict__ w2b,
                           float* __restrict__ out) {
  constexpr int NT = 32;  // K = 2048 / 64
  __shared__ __attribute__((aligned(16))) u16 lA[2][256 * 64];
  __shared__ __attribute__((aligned(16))) u16 lB[2][256 * 64];

  int bid = blockIdx.x;
  int sw = (bid & 7) * 64 + (bid >> 3);   // 512 wg
  int nblk = sw >> 7;
  int rem = sw & 127;
  int mt = rem >> 1, nt = rem & 1;

  int tid = threadIdx.x, w = tid >> 6, ln = tid & 63;
  int mi = w >> 2, nj = w & 3;
  int l15 = ln & 15, l4 = ln >> 4;
  int lr = ln >> 3, ln8 = ln & 7;

  int cx0 = ((l4 ^ (l15 & 7)) << 4);
  int cx1 = (((4 + l4) ^ (l15 & 7)) << 4);
  int aOff0 = (mi * 128 + l15) * 128 + cx0;
  int aOff1 = (mi * 128 + l15) * 128 + cx1;
  int bOff0 = (nj * 64 + l15) * 128 + cx0;
  int bOff1 = (nj * 64 + l15) * 128 + cx1;

  int u0t = w * 8, u1t = 64 + w * 8;
  int dA0 = u0t * 128, dA1 = (64 + u1t) * 128;     // A: stg<64,128>
  int rbB0 = ((u0t >> 5) << 6) + (u0t & 31);
  int rbB1 = ((u1t >> 5) << 6) + (u1t & 31);
  int dB0 = rbB0 * 128, dB1 = rbB1 * 128;          // B: stg<32,64>
  int gaA0 = u0t * 8192, gaA1 = (64 + u1t) * 8192;
  int gaB0 = rbB0 * 2048, gaB1 = rbB1 * 2048;
  int swzg = (ln8 ^ lr) << 3;

  const u16* gA = hmat + (size_t)(mt * 256) * 8192 + nblk * 2048 + lr * 8192 + swzg;
  const u16* gB = w2b + (size_t)nblk * (512 * 2048) + (size_t)(nt * 256) * 2048 + lr * 2048 + swzg;

  f32x4 acc[8][4];
#pragma unroll
  for (int i = 0; i < 8; i++)
#pragma unroll
    for (int j = 0; j < 4; j++) acc[i][j] = (f32x4){0.f, 0.f, 0.f, 0.f};

  // prologue: t0.{Alo,Bhi,Ahi,Blo}, t1.{Alo,Bhi,Ahi}
  gload_lds16(gA + gaA0,           (u16*)((char*)lA + dA0));
  gload_lds16(gA + gaA1,           (u16*)((char*)lA + dA1));
  gload_lds16(gB + gaB0 + 65536,   (u16*)((char*)lB + dB0 + 4096));
  gload_lds16(gB + gaB1 + 65536,   (u16*)((char*)lB + dB1 + 4096));
  gload_lds16(gA + gaA0 + 524288,  (u16*)((char*)lA + dA0 + 8192));
  gload_lds16(gA + gaA1 + 524288,  (u16*)((char*)lA + dA1 + 8192));
  gload_lds16(gB + gaB0,           (u16*)((char*)lB + dB0));
  gload_lds16(gB + gaB1,           (u16*)((char*)lB + dB1));
  gload_lds16(gA + 64 + gaA0,          (u16*)((char*)lA + 32768 + dA0));
  gload_lds16(gA + 64 + gaA1,          (u16*)((char*)lA + 32768 + dA1));
  gload_lds16(gB + 64 + gaB0 + 65536,  (u16*)((char*)lB + 32768 + dB0 + 4096));
  gload_lds16(gB + 64 + gaB1 + 65536,  (u16*)((char*)lB + 32768 + dB1 + 4096));
  gload_lds16(gA + 64 + gaA0 + 524288, (u16*)((char*)lA + 32768 + dA0 + 8192));
  gload_lds16(gA + 64 + gaA1 + 524288, (u16*)((char*)lA + 32768 + dA1 + 8192));
  gA += 128; gB += 64;   // gA at t2 (A stages are t+2); gB at t1 (Blo t+1, Bhi t+2 via +64)
  asm volatile("s_waitcnt vmcnt(6)" ::: "memory");
  __builtin_amdgcn_s_barrier();

  int sCur = 0, sNxt = 32768;
  bf16x8 aF[4][2], bLo[2][2], bHi[2][2];

  for (int kt = 0; kt < NT; ++kt) {
    const char* pA0 = (const char*)lA + (sCur + aOff0);
    const char* pA1 = (const char*)lA + (sCur + aOff1);
    const char* pB0 = (const char*)lB + (sCur + bOff0);
    const char* pB1p = (const char*)lB + (sCur + bOff1);
    bool s1 = (kt + 1 < NT), s2 = (kt + 2 < NT);

    // ---- P0: read A f0-3 + B-lo; stage t+1.B-lo (other buf)
#pragma unroll
    for (int f = 0; f < 4; ++f) {
      aF[f][0] = RD(pA0 + f * 2048); aF[f][1] = RD(pA1 + f * 2048);
    }
#pragma unroll
    for (int g = 0; g < 2; ++g) {
      bLo[g][0] = RD(pB0 + g * 2048); bLo[g][1] = RD(pB1p + g * 2048);
    }
    if (s1) {
      gload_lds16(gB + gaB0, (u16*)((char*)lB + sNxt + dB0));
      gload_lds16(gB + gaB1, (u16*)((char*)lB + sNxt + dB1));
    }
    asm volatile("s_waitcnt lgkmcnt(8)" ::: "memory");
    PH_BEGIN();
#pragma unroll
    for (int f = 0; f < 4; ++f)
#pragma unroll
      for (int g = 0; g < 2; ++g)
#pragma unroll
        for (int ks = 0; ks < 2; ++ks)
          acc[f][g] = __builtin_amdgcn_mfma_f32_16x16x32_bf16(aF[f][ks], bLo[g][ks], acc[f][g], 0, 0, 0);
    PH_END();

    // ---- P1: read B-hi; stage t+2.A-lo (cur buf)
#pragma unroll
    for (int g = 0; g < 2; ++g) {
      bHi[g][0] = RD(pB0 + 4096 + g * 2048); bHi[g][1] = RD(pB1p + 4096 + g * 2048);
    }
    if (s2) {
      gload_lds16(gA + gaA0, (u16*)((char*)lA + sCur + dA0));
      gload_lds16(gA + gaA1, (u16*)((char*)lA + sCur + dA1));
    }
    PH_BEGIN();
#pragma unroll
    for (int f = 0; f < 4; ++f)
#pragma unroll
      for (int g = 0; g < 2; ++g)
#pragma unroll
        for (int ks = 0; ks < 2; ++ks)
          acc[f][2 + g] = __builtin_amdgcn_mfma_f32_16x16x32_bf16(aF[f][ks], bHi[g][ks], acc[f][2 + g], 0, 0, 0);
    PH_END();

    // ---- P2: read A f4-7; stage t+2.B-hi (cur buf)
#pragma unroll
    for (int f = 0; f < 4; ++f) {
      aF[f][0] = RD(pA0 + 8192 + f * 2048); aF[f][1] = RD(pA1 + 8192 + f * 2048);
    }
    if (s2) {
      gload_lds16(gB + 64 + gaB0 + 65536, (u16*)((char*)lB + sCur + dB0 + 4096));
      gload_lds16(gB + 64 + gaB1 + 65536, (u16*)((char*)lB + sCur + dB1 + 4096));
    }
    PH_BEGIN();
#pragma unroll
    for (int f = 0; f < 4; ++f)
#pragma unroll
      for (int g = 0; g < 2; ++g)
#pragma unroll
        for (int ks = 0; ks < 2; ++ks)
          acc[4 + f][g] = __builtin_amdgcn_mfma_f32_16x16x32_bf16(aF[f][ks], bLo[g][ks], acc[4 + f][g], 0, 0, 0);
    PH_END();

    // ---- P3: stage t+2.A-hi (cur buf); trailing counted vmcnt
    if (s2) {
      gload_lds16(gA + gaA0 + 524288, (u16*)((char*)lA + sCur + dA0 + 8192));
      gload_lds16(gA + gaA1 + 524288, (u16*)((char*)lA + sCur + dA1 + 8192));
    }
    PH_BEGIN();
#pragma unroll
    for (int f = 0; f < 4; ++f)
#pragma unroll
      for (int g = 0; g < 2; ++g)
#pragma unroll
        for (int ks = 0; ks < 2; ++ks)
          acc[4 + f][2 + g] = __builtin_amdgcn_mfma_f32_16x16x32_bf16(aF[f][ks], bHi[g][ks], acc[4 + f][2 + g], 0, 0, 0);
    __builtin_amdgcn_s_setprio(0);
    if (kt < NT - 2)       asm volatile("s_waitcnt vmcnt(6)" ::: "memory");
    else if (kt == NT - 2) asm volatile("s_waitcnt vmcnt(0)" ::: "memory");
    __builtin_amdgcn_s_barrier();
    gA += 64; gB += 64;
    sCur ^= 32768; sNxt ^= 32768;
  }

  float* Ob = out + (size_t)(mt * 256 + mi * 128) * 2048 + nblk * 512 + nt * 256 + nj * 64;
#pragma unroll
  for (int f = 0; f < 8; ++f)
#pragma unroll
    for (int g = 0; g < 4; ++g) {
      int col = g * 16 + l15;
#pragma unroll
      for (int r = 0; r < 4; ++r) {
        int row = f * 16 + l4 * 4 + r;
        Ob[(size_t)row * 2048 + col] = acc[f][g][r];
      }
    }
}

extern "C" void kernel_launch(void* const* d_in, const int* in_sizes, int n_in,
                              void* d_out, int out_size, void* d_ws, size_t ws_size,
                              hipStream_t stream) {
  const float* x  = (const float*)d_in[0];
  const float* w1 = (const float*)d_in[1];
  const float* w3 = (const float*)d_in[2];
  const float* w2 = (const float*)d_in[3];

  char* ws = (char*)d_ws;
  u16* xb  = (u16*)(ws);                 // 64 MiB
  u16* w1b = (u16*)(ws + 67108864);      // 8 MiB
  u16* w3b = (u16*)(ws + 75497472);
  u16* w2b = (u16*)(ws + 83886080);
  u16* h   = (u16*)(ws + 92274688);      // 256 MiB

  cvt_f32_bf16<<<2048, 256, 0, stream>>>(x,  xb,  33554432 / 8);
  cvt_f32_bf16<<<2048, 256, 0, stream>>>(w1, w1b, 4194304 / 8);
  cvt_f32_bf16<<<2048, 256, 0, stream>>>(w3, w3b, 4194304 / 8);
  cvt_f32_bf16<<<2048, 256, 0, stream>>>(w2, w2b, 4194304 / 8);

  gemm_gateup8<<<4096, 512, 0, stream>>>(xb, w1b, w3b, h);
  gemm_down8<<<512, 512, 0, stream>>>(h, w2b, (float*)d_out);
}